// Round 4
// baseline (4591.908 us; speedup 1.0000x reference)
//
#include <hip/hip_runtime.h>
#include <hip/hip_bf16.h>

typedef __bf16 bf16_t;
typedef bf16_t bf16x8 __attribute__((ext_vector_type(8)));
typedef float f32x4 __attribute__((ext_vector_type(4)));

#define D_DIM 300
#define TPB 320

__device__ inline f32x4 mfma16(bf16x8 a, bf16x8 b, f32x4 c) {
  return __builtin_amdgcn_mfma_f32_16x16x32_bf16(a, b, c, 0, 0, 0);
}

__device__ inline void split2(float x, unsigned short& h, unsigned short& l) {
  bf16_t hb = (bf16_t)x;
  float hf = (float)hb;
  bf16_t lb = (bf16_t)(x - hf);
  h = __builtin_bit_cast(unsigned short, hb);
  l = __builtin_bit_cast(unsigned short, lb);
}

__device__ inline uint4 pack8(const unsigned short* s) {
  return make_uint4((unsigned int)s[0] | ((unsigned int)s[1] << 16),
                    (unsigned int)s[2] | ((unsigned int)s[3] << 16),
                    (unsigned int)s[4] | ((unsigned int)s[5] << 16),
                    (unsigned int)s[6] | ((unsigned int)s[7] << 16));
}

// ---------------- utility ----------------

__global__ void zero_u32_kernel(unsigned int* __restrict__ p, long long n) {
  long long i = (long long)blockIdx.x * blockDim.x + threadIdx.x;
  long long s = (long long)gridDim.x * blockDim.x;
  for (; i < n; i += s) p[i] = 0u;
}

// ---------------- graph prep ----------------

__global__ void init_h_kernel(const int* __restrict__ atom, const int* __restrict__ chir,
                              const float* __restrict__ e1, const float* __restrict__ e2,
                              float* __restrict__ h) {
  int n = blockIdx.x;
  int d = threadIdx.x;
  if (d >= D_DIM) return;
  int a = atom[n], c = chir[n];
  h[(size_t)n * D_DIM + d] = e1[a * D_DIM + d] + e2[c * D_DIM + d];
}

__global__ void combo_kernel(const float* __restrict__ ee1, const float* __restrict__ ee2,
                             float* __restrict__ ct) {
  int l = blockIdx.x / 13, c = blockIdx.x % 13;
  int d = threadIdx.x;
  if (d >= D_DIM) return;
  int bt = (c < 12) ? (c / 3) : 4;
  int bd = (c < 12) ? (c % 3) : 0;
  ct[((size_t)(l * 13 + c)) * D_DIM + d] =
      ee1[(size_t)(l * 5 + bt) * D_DIM + d] + ee2[(size_t)(l * 3 + bd) * D_DIM + d];
}

__global__ void edge_combo_kernel(const int* __restrict__ bt, const int* __restrict__ bd,
                                  int* __restrict__ ec, int E) {
  int e = blockIdx.x * blockDim.x + threadIdx.x;
  if (e < E) ec[e] = bt[e] * 3 + bd[e];
}

// ---------------- CSR build ----------------

__global__ void csr_count_kernel(const int* __restrict__ row, int* __restrict__ deg, int E) {
  int e = blockIdx.x * blockDim.x + threadIdx.x;
  if (e < E) atomicAdd(&deg[row[e]], 1);
}

#define SCAN_T 1024
__global__ void scan_kernel(const int* __restrict__ deg, int* __restrict__ off,
                            int* __restrict__ cur, int n) {
  __shared__ int buf[SCAN_T];
  __shared__ int carry;
  int t = threadIdx.x;
  if (t == 0) carry = 0;
  __syncthreads();
  for (int base = 0; base < n; base += SCAN_T) {
    int i = base + t;
    int v = (i < n) ? deg[i] : 0;
    buf[t] = v;
    __syncthreads();
#pragma unroll
    for (int s = 1; s < SCAN_T; s <<= 1) {
      int add = (t >= s) ? buf[t - s] : 0;
      __syncthreads();
      buf[t] += add;
      __syncthreads();
    }
    int exc = buf[t] - v + carry;
    if (i < n) {
      off[i] = exc;
      cur[i] = exc;
    }
    __syncthreads();
    if (t == SCAN_T - 1) carry += buf[SCAN_T - 1];
    __syncthreads();
  }
  if (t == 0) off[n] = carry;
}

__global__ void csr_fill_kernel(const int* __restrict__ row, const int* __restrict__ col,
                                const int* __restrict__ ec, int* __restrict__ cur,
                                int* __restrict__ scol, int* __restrict__ sec, int E) {
  int e = blockIdx.x * blockDim.x + threadIdx.x;
  if (e < E) {
    int r = row[e];
    int p = atomicAdd(&cur[r], 1);
    scol[p] = col[e];
    sec[p] = ec[e];
  }
}

// ---------------- gather (BN affine + relu folded into the h reads) ----------------
// agg[n] = T(h[n]) + ct[12] + sum_nbr( T(h[col]) + ct[ec] ), T(x) = relu?(sc*x+sh)

template <bool TRANS, bool RELU>
__global__ __launch_bounds__(256) void gather_kernel(
    const float* __restrict__ h, const float* __restrict__ sc, const float* __restrict__ sh,
    const int* __restrict__ off, const int* __restrict__ scol, const int* __restrict__ sec,
    const float* __restrict__ ct_l, float* __restrict__ agg, int N) {
  int wid = threadIdx.x >> 6;
  int lane = threadIdx.x & 63;
  int n = blockIdx.x * 4 + wid;
  if (n >= N) return;
  float scv[5], shv[5];
#pragma unroll
  for (int c = 0; c < 5; ++c) {
    int d = c * 64 + lane;
    if (TRANS) {
      scv[c] = (d < D_DIM) ? sc[d] : 0.f;
      shv[c] = (d < D_DIM) ? sh[d] : 0.f;
    } else {
      scv[c] = 1.f;
      shv[c] = 0.f;
    }
  }
  float acc[5];
#pragma unroll
  for (int c = 0; c < 5; ++c) {
    int d = c * 64 + lane;
    if (d < D_DIM) {
      float x = h[(size_t)n * D_DIM + d];
      float v = TRANS ? fmaf(x, scv[c], shv[c]) : x;
      if (RELU) v = fmaxf(v, 0.f);
      acc[c] = v + ct_l[12 * D_DIM + d];
    } else {
      acc[c] = 0.f;
    }
  }
  int p0 = off[n], p1 = off[n + 1];
  for (int p = p0; p < p1; ++p) {
    int scn = scol[p];
    int se = sec[p];
    const float* hp = h + (size_t)scn * D_DIM;
    const float* cp = ct_l + se * D_DIM;
#pragma unroll
    for (int c = 0; c < 5; ++c) {
      int d = c * 64 + lane;
      if (d < D_DIM) {
        float x = hp[d];
        float v = TRANS ? fmaf(x, scv[c], shv[c]) : x;
        if (RELU) v = fmaxf(v, 0.f);
        acc[c] += v + cp[d];
      }
    }
  }
#pragma unroll
  for (int c = 0; c < 5; ++c) {
    int d = c * 64 + lane;
    if (d < D_DIM) agg[(size_t)n * D_DIM + d] = acc[c];
  }
}

// ---------------- BatchNorm stats ----------------

__global__ void bn_stats_kernel(const float* __restrict__ x, float* __restrict__ stats, int N) {
  int d = threadIdx.x;
  if (d >= D_DIM) return;
  float s = 0.f, s2 = 0.f;
  for (int n = blockIdx.x; n < N; n += gridDim.x) {
    float v = x[(size_t)n * D_DIM + d];
    s += v;
    s2 += v * v;
  }
  atomicAdd(&stats[d], s);
  atomicAdd(&stats[D_DIM + d], s2);
}

__global__ void bn_final_kernel(const float* __restrict__ stats, const float* __restrict__ gamma_l,
                                const float* __restrict__ beta_l, float* __restrict__ bnsc,
                                float* __restrict__ bnsh, int N) {
  int d = threadIdx.x;
  if (d >= D_DIM) return;
  float inv_n = 1.0f / (float)N;
  float mean = stats[d] * inv_n;
  float var = stats[D_DIM + d] * inv_n - mean * mean;
  float inv = rsqrtf(var + 1e-5f);
  float sc = gamma_l[d] * inv;
  bnsc[d] = sc;
  bnsh[d] = beta_l[d] - mean * sc;
}

// ---------------- pooling (BN affine folded) ----------------

__global__ void pool_scatter_kernel(const float* __restrict__ h, const float* __restrict__ sc,
                                    const float* __restrict__ sh, const int* __restrict__ batch,
                                    float* __restrict__ pool, int* __restrict__ pcnt) {
  int n = blockIdx.x;
  int d = threadIdx.x;
  if (d >= D_DIM) return;
  int g = batch[n];
  float v = fmaf(h[(size_t)n * D_DIM + d], sc[d], sh[d]);
  atomicAdd(&pool[(size_t)g * D_DIM + d], v);
  if (d == 0) atomicAdd(&pcnt[g], 1);
}

__global__ void pool_div_kernel(float* __restrict__ pool, const int* __restrict__ pcnt) {
  int g = blockIdx.x;
  int d = threadIdx.x;
  if (d >= D_DIM) return;
  float c = (float)pcnt[g];
  if (c < 1.f) c = 1.f;
  pool[(size_t)g * D_DIM + d] /= c;
}

// ---------------- weight pack: W[K][Nw] fp32 -> MFMA-fragment-order hi/lo bf16 ----
// layout: frag (colTile ct, kstep ks): 64 lanes x 8 elems contiguous.
// lane l holds col = ct*16+(l&15), k = ks*32+(l>>4)*8 .. +7.

__global__ void wpack_kernel(const float* __restrict__ W, bf16_t* __restrict__ Th,
                             bf16_t* __restrict__ Tl, int K, int Nw) {
  int ct = blockIdx.x;
  int ks = blockIdx.y;
  int l = threadIdx.x;
  int col = ct * 16 + (l & 15);
  int kb = ks * 32 + (l >> 4) * 8;
  unsigned short hs[8], ls[8];
#pragma unroll
  for (int j = 0; j < 8; ++j) {
    int k = kb + j;
    float v = (k < K && col < Nw) ? W[(size_t)k * Nw + col] : 0.f;
    split2(v, hs[j], ls[j]);
  }
  size_t off = ((size_t)(ct * gridDim.y + ks) * 64 + l) * 8;
  *(uint4*)(Th + off) = pack8(hs);
  *(uint4*)(Tl + off) = pack8(ls);
}

// ---------------- MFMA GEMM v2: per-block full-N, A staged once ----------------
// C[M,N] = act(A[M,K] @ B[K,N] + bias). Block: 64 rows, 4 waves, each wave owns
// 16 cols of every 64-col tile. A LDS-resident (hi/lo split if fp32), XOR-swizzled.
// B pre-packed in fragment order (coalesced 16B/lane loads, L2-hot).
// KP: padded K (mult 64). NT: N-tiles (N<=NT*64). NC: tiles per K-sweep chunk.

template <int KP, int NT, int NC, bool A_SPLIT, bool RELU, bool OUT_BF16>
__global__ __launch_bounds__(256, 2) void mfma_gemm2(
    const void* __restrict__ Aptr, const bf16_t* __restrict__ Bh,
    const bf16_t* __restrict__ Bl, const float* __restrict__ bias, void* __restrict__ Cptr,
    int M, int N, int K, int astride, int cstride) {
  constexpr int KPB = KP * 2;  // LDS bytes per row (KP mult 64 -> KPB mult 128)
  constexpr int KSTEPS = KP / 32;
  constexpr int LDS_HALF = 64 * KPB;
  __shared__ __align__(16) char ldsA[(A_SPLIT ? 2 : 1) * LDS_HALF];

  const int t = threadIdx.x;
  const int m0 = blockIdx.x * 64;
  const int w = t >> 6;
  const int lane = t & 63;
  const int lrow = lane & 15;
  const int lk = lane >> 4;

#define SWZ(row, kbyte) ((row) * KPB + ((kbyte) ^ (((row) & 7) << 4)))

  // ---- stage A into LDS (once) ----
  {
    const int r = t >> 2;
    const int seg = t & 3;
    const int gr = m0 + r;
    constexpr int KQ = KP / 4;  // elems per segment
    if constexpr (A_SPLIT) {
      const float* arow = (const float*)Aptr + (size_t)gr * astride;
      for (int j0 = seg * KQ; j0 < (seg + 1) * KQ; j0 += 16) {
        float va[16];
        if (gr < M && j0 + 16 <= K) {
          const float4* fp = (const float4*)(arow + j0);
#pragma unroll
          for (int q = 0; q < 4; ++q) {
            float4 x = fp[q];
            va[4 * q] = x.x;
            va[4 * q + 1] = x.y;
            va[4 * q + 2] = x.z;
            va[4 * q + 3] = x.w;
          }
        } else {
#pragma unroll
          for (int j = 0; j < 16; ++j)
            va[j] = (gr < M && j0 + j < K) ? arow[j0 + j] : 0.f;
        }
        unsigned short hs[16], ls[16];
#pragma unroll
        for (int j = 0; j < 16; ++j) split2(va[j], hs[j], ls[j]);
        int kb = j0 * 2;
        *(uint4*)(ldsA + SWZ(r, kb)) = pack8(hs);
        *(uint4*)(ldsA + SWZ(r, kb + 16)) = pack8(hs + 8);
        *(uint4*)(ldsA + LDS_HALF + SWZ(r, kb)) = pack8(ls);
        *(uint4*)(ldsA + LDS_HALF + SWZ(r, kb + 16)) = pack8(ls + 8);
      }
    } else {
      const unsigned short* arow = (const unsigned short*)Aptr + (size_t)gr * astride;
      for (int j0 = seg * KQ; j0 < (seg + 1) * KQ; j0 += 16) {
        uint4 q0, q1;
        if (gr < M && j0 + 16 <= K) {
          const uint4* up = (const uint4*)(arow + j0);
          q0 = up[0];
          q1 = up[1];
        } else {
          unsigned short tmp[16];
#pragma unroll
          for (int j = 0; j < 16; ++j)
            tmp[j] = (gr < M && j0 + j < K) ? arow[j0 + j] : (unsigned short)0;
          q0 = pack8(tmp);
          q1 = pack8(tmp + 8);
        }
        int kb = j0 * 2;
        *(uint4*)(ldsA + SWZ(r, kb)) = q0;
        *(uint4*)(ldsA + SWZ(r, kb + 16)) = q1;
      }
    }
  }
  __syncthreads();

  // ---- compute: chunks of NC col-tiles, K-outer within chunk ----
  for (int nc0 = 0; nc0 < NT; nc0 += NC) {
    f32x4 acc[NC][4] = {};
    for (int ks = 0; ks < KSTEPS; ++ks) {
      const int kbyte = ks * 64 + lk * 16;
      bf16x8 ah[4], al[4];
#pragma unroll
      for (int i = 0; i < 4; ++i) {
        int row = i * 16 + lrow;
        ah[i] = *(const bf16x8*)(const void*)(ldsA + SWZ(row, kbyte));
        if constexpr (A_SPLIT)
          al[i] = *(const bf16x8*)(const void*)(ldsA + LDS_HALF + SWZ(row, kbyte));
      }
#pragma unroll
      for (int nti = 0; nti < NC; ++nti) {
        int colTile = (nc0 + nti) * 4 + w;
        size_t bo = ((size_t)(colTile * KSTEPS + ks) * 64 + lane) * 8;
        bf16x8 bh = *(const bf16x8*)(const void*)(Bh + bo);
        bf16x8 bl = *(const bf16x8*)(const void*)(Bl + bo);
#pragma unroll
        for (int i = 0; i < 4; ++i) {
          acc[nti][i] = mfma16(ah[i], bh, acc[nti][i]);
          acc[nti][i] = mfma16(ah[i], bl, acc[nti][i]);
          if constexpr (A_SPLIT) acc[nti][i] = mfma16(al[i], bh, acc[nti][i]);
        }
      }
    }
    // ---- epilogue for this chunk ----
#pragma unroll
    for (int nti = 0; nti < NC; ++nti) {
      int gcol = (nc0 + nti) * 64 + w * 16 + lrow;
      if (gcol >= N) continue;
      float bsv = bias[gcol];
#pragma unroll
      for (int i = 0; i < 4; ++i) {
#pragma unroll
        for (int r4 = 0; r4 < 4; ++r4) {
          int grow = m0 + i * 16 + lk * 4 + r4;
          if (grow < M) {
            float v = acc[nti][i][r4] + bsv;
            if (RELU) v = fmaxf(v, 0.f);
            if constexpr (OUT_BF16)
              ((bf16_t*)Cptr)[(size_t)grow * cstride + gcol] = (bf16_t)v;
            else
              ((float*)Cptr)[(size_t)grow * cstride + gcol] = v;
          }
        }
      }
    }
  }
#undef SWZ
}

// ---------------- launch ----------------

extern "C" void kernel_launch(void* const* d_in, const int* in_sizes, int n_in,
                              void* d_out, int out_size, void* d_ws, size_t ws_size,
                              hipStream_t stream) {
  const int* atom = (const int*)d_in[0];
  const int* chir = (const int*)d_in[1];
  const int* eidx = (const int*)d_in[2];
  const int* btype = (const int*)d_in[3];
  const int* bdir = (const int*)d_in[4];
  const int* batch = (const int*)d_in[5];
  const float* x_emb1 = (const float*)d_in[6];
  const float* x_emb2 = (const float*)d_in[7];
  const float* ee1 = (const float*)d_in[8];
  const float* ee2 = (const float*)d_in[9];
  const float* W1 = (const float*)d_in[10];
  const float* b1 = (const float*)d_in[11];
  const float* W2 = (const float*)d_in[12];
  const float* b2 = (const float*)d_in[13];
  const float* gamma = (const float*)d_in[14];
  const float* beta = (const float*)d_in[15];
  const float* featW = (const float*)d_in[16];
  const float* featb = (const float*)d_in[17];
  const float* projW = (const float*)d_in[18];
  const float* projb = (const float*)d_in[19];

  const int N = in_sizes[0];
  const int E = in_sizes[2] / 2;
  const int PROJ = in_sizes[19];
  const int FEAT = in_sizes[17];
  const int G = out_size / PROJ;
  const int L = in_sizes[11] / (2 * D_DIM);
  const int D2 = 2 * D_DIM;  // 600

  const int* row = eidx;
  const int* col = eidx + E;

  // GEMM geometry (compile-time in templates; mirrored here)
  const int KP1 = 320, NT1 = 10;  // W1: K=300, N=600 -> NPAD 640
  const int KP2 = 640, NT2 = 5;   // W2: K=600, N=300 -> NPAD 320
  const int KPF = 320, NTF = 8;   // feat: K=300, N=512
  const int KPP = 512, NTP = 4;   // proj: K=512, N=256
  const int SZ1 = NT1 * 64 * KP1; // elems per table
  const int SZ2 = NT2 * 64 * KP2;
  const int SZF = NTF * 64 * KPF;
  const int SZP = NTP * 64 * KPP;

  // ---- workspace ----
  char* ws = (char*)d_ws;
  size_t off = 0;
  auto alloc = [&](size_t bytes) -> char* {
    char* p = ws + off;
    off += (bytes + 255) & ~(size_t)255;
    return p;
  };
  float* B0 = (float*)alloc((size_t)N * D_DIM * 4);
  float* B1 = (float*)alloc((size_t)N * D_DIM * 4);
  float* CT = (float*)alloc((size_t)L * 13 * D_DIM * 4);
  int* EC = (int*)alloc((size_t)E * 4);
  int* DEG = (int*)alloc((size_t)N * 4);
  int* OFF = (int*)alloc((size_t)(N + 1) * 4);
  int* CUR = (int*)alloc((size_t)N * 4);
  int* SCOL = (int*)alloc((size_t)E * 4);
  int* SEC = (int*)alloc((size_t)E * 4);
  float* STATS = (float*)alloc(2 * D_DIM * 4);
  float* BNSC = (float*)alloc(D_DIM * 4);
  float* BNSH = (float*)alloc(D_DIM * 4);
  bf16_t* W1Th = (bf16_t*)alloc((size_t)L * SZ1 * 2);
  bf16_t* W1Tl = (bf16_t*)alloc((size_t)L * SZ1 * 2);
  bf16_t* W2Th = (bf16_t*)alloc((size_t)L * SZ2 * 2);
  bf16_t* W2Tl = (bf16_t*)alloc((size_t)L * SZ2 * 2);
  bf16_t* FTh = (bf16_t*)alloc((size_t)SZF * 2);
  bf16_t* FTl = (bf16_t*)alloc((size_t)SZF * 2);
  bf16_t* PTh = (bf16_t*)alloc((size_t)SZP * 2);
  bf16_t* PTl = (bf16_t*)alloc((size_t)SZP * 2);
  (void)ws_size;

  // ---- prep ----
  init_h_kernel<<<N, TPB, 0, stream>>>(atom, chir, x_emb1, x_emb2, B0);
  combo_kernel<<<L * 13, TPB, 0, stream>>>(ee1, ee2, CT);
  edge_combo_kernel<<<(E + 255) / 256, 256, 0, stream>>>(btype, bdir, EC, E);

  zero_u32_kernel<<<(N + 255) / 256, 256, 0, stream>>>((unsigned int*)DEG, N);
  csr_count_kernel<<<(E + 255) / 256, 256, 0, stream>>>(row, DEG, E);
  scan_kernel<<<1, SCAN_T, 0, stream>>>(DEG, OFF, CUR, N);
  csr_fill_kernel<<<(E + 255) / 256, 256, 0, stream>>>(row, col, EC, CUR, SCOL, SEC, E);

  for (int l = 0; l < L; ++l) {
    wpack_kernel<<<dim3(NT1 * 4, KP1 / 32), 64, 0, stream>>>(
        W1 + (size_t)l * D_DIM * D2, W1Th + (size_t)l * SZ1, W1Tl + (size_t)l * SZ1, D_DIM, D2);
    wpack_kernel<<<dim3(NT2 * 4, KP2 / 32), 64, 0, stream>>>(
        W2 + (size_t)l * D2 * D_DIM, W2Th + (size_t)l * SZ2, W2Tl + (size_t)l * SZ2, D2, D_DIM);
  }
  wpack_kernel<<<dim3(NTF * 4, KPF / 32), 64, 0, stream>>>(featW, FTh, FTl, D_DIM, FEAT);
  wpack_kernel<<<dim3(NTP * 4, KPP / 32), 64, 0, stream>>>(projW, PTh, PTl, FEAT, PROJ);

  float* hbuf = B0;  // raw h2 of previous layer (layer 0: initial h)
  float* sbuf = B1;
  const int gblocks = (N + 63) / 64;

  for (int l = 0; l < L; ++l) {
    const float* ctl = CT + (size_t)l * 13 * D_DIM;
    // gather: agg(sbuf) = T(h) + self-const + sum_nbr(T(h[col]) + ee)
    if (l == 0)
      gather_kernel<false, false><<<(N + 3) / 4, 256, 0, stream>>>(hbuf, BNSC, BNSH, OFF, SCOL,
                                                                   SEC, ctl, sbuf, N);
    else
      gather_kernel<true, true><<<(N + 3) / 4, 256, 0, stream>>>(hbuf, BNSC, BNSH, OFF, SCOL,
                                                                 SEC, ctl, sbuf, N);
    // hid = relu(agg @ W1 + b1) -> bf16 [N][600] into hbuf (prev h dead)
    mfma_gemm2<320, 10, 5, true, true, true><<<gblocks, 256, 0, stream>>>(
        sbuf, W1Th + (size_t)l * SZ1, W1Tl + (size_t)l * SZ1, b1 + (size_t)l * D2, hbuf, N, D2,
        D_DIM, D_DIM, D2);
    // h2 = hid @ W2 + b2 -> fp32 [N][300] into sbuf (agg dead)
    mfma_gemm2<640, 5, 5, false, false, false><<<gblocks, 256, 0, stream>>>(
        hbuf, W2Th + (size_t)l * SZ2, W2Tl + (size_t)l * SZ2, b2 + (size_t)l * D_DIM, sbuf, N,
        D_DIM, D2, D2, D_DIM);
    // BN stats of raw h2 (affine folded into next consumer)
    zero_u32_kernel<<<2, 320, 0, stream>>>((unsigned int*)STATS, 2 * D_DIM);
    bn_stats_kernel<<<512, TPB, 0, stream>>>(sbuf, STATS, N);
    bn_final_kernel<<<1, TPB, 0, stream>>>(STATS, gamma + (size_t)l * D_DIM,
                                           beta + (size_t)l * D_DIM, BNSC, BNSH, N);
    float* tmp = hbuf;
    hbuf = sbuf;
    sbuf = tmp;
  }

  // final raw h2 in hbuf (BN of last layer folded into pool); sbuf free
  float* POOL = sbuf;
  int* PCNT = (int*)(POOL + (size_t)G * D_DIM);
  float* FEATB = (float*)(PCNT + G);

  {
    long long nz = (long long)G * D_DIM + G;
    int blocks = (int)((nz + 255) / 256);
    if (blocks > 2048) blocks = 2048;
    zero_u32_kernel<<<blocks, 256, 0, stream>>>((unsigned int*)POOL, nz);
  }
  pool_scatter_kernel<<<N, TPB, 0, stream>>>(hbuf, BNSC, BNSH, batch, POOL, PCNT);
  pool_div_kernel<<<G, TPB, 0, stream>>>(POOL, PCNT);

  mfma_gemm2<320, 8, 4, true, false, false><<<(G + 63) / 64, 256, 0, stream>>>(
      POOL, FTh, FTl, featb, FEATB, G, FEAT, D_DIM, D_DIM, FEAT);
  mfma_gemm2<512, 4, 4, true, false, false><<<(G + 63) / 64, 256, 0, stream>>>(
      FEATB, PTh, PTl, projb, d_out, G, PROJ, FEAT, FEAT, PROJ);
}

// Round 5
// 3405.194 us; speedup vs baseline: 1.3485x; 1.3485x over previous
//
#include <hip/hip_runtime.h>
#include <hip/hip_bf16.h>

typedef __bf16 bf16_t;
typedef bf16_t bf16x8 __attribute__((ext_vector_type(8)));
typedef float f32x4 __attribute__((ext_vector_type(4)));

#define D_DIM 300
#define TPB 320

__device__ inline f32x4 mfma16(bf16x8 a, bf16x8 b, f32x4 c) {
  return __builtin_amdgcn_mfma_f32_16x16x32_bf16(a, b, c, 0, 0, 0);
}

__device__ inline void split2(float x, unsigned short& h, unsigned short& l) {
  bf16_t hb = (bf16_t)x;
  float hf = (float)hb;
  bf16_t lb = (bf16_t)(x - hf);
  h = __builtin_bit_cast(unsigned short, hb);
  l = __builtin_bit_cast(unsigned short, lb);
}

__device__ inline uint4 pack8(const unsigned short* s) {
  return make_uint4((unsigned int)s[0] | ((unsigned int)s[1] << 16),
                    (unsigned int)s[2] | ((unsigned int)s[3] << 16),
                    (unsigned int)s[4] | ((unsigned int)s[5] << 16),
                    (unsigned int)s[6] | ((unsigned int)s[7] << 16));
}

// ---------------- utility ----------------

__global__ void zero_u32_kernel(unsigned int* __restrict__ p, long long n) {
  long long i = (long long)blockIdx.x * blockDim.x + threadIdx.x;
  long long s = (long long)gridDim.x * blockDim.x;
  for (; i < n; i += s) p[i] = 0u;
}

// ---------------- graph prep ----------------

__global__ void init_h_kernel(const int* __restrict__ atom, const int* __restrict__ chir,
                              const float* __restrict__ e1, const float* __restrict__ e2,
                              float* __restrict__ h) {
  int n = blockIdx.x;
  int d = threadIdx.x;
  if (d >= D_DIM) return;
  int a = atom[n], c = chir[n];
  h[(size_t)n * D_DIM + d] = e1[a * D_DIM + d] + e2[c * D_DIM + d];
}

__global__ void combo_kernel(const float* __restrict__ ee1, const float* __restrict__ ee2,
                             float* __restrict__ ct) {
  int l = blockIdx.x / 13, c = blockIdx.x % 13;
  int d = threadIdx.x;
  if (d >= D_DIM) return;
  int bt = (c < 12) ? (c / 3) : 4;
  int bd = (c < 12) ? (c % 3) : 0;
  ct[((size_t)(l * 13 + c)) * D_DIM + d] =
      ee1[(size_t)(l * 5 + bt) * D_DIM + d] + ee2[(size_t)(l * 3 + bd) * D_DIM + d];
}

__global__ void edge_combo_kernel(const int* __restrict__ bt, const int* __restrict__ bd,
                                  int* __restrict__ ec, int E) {
  int e = blockIdx.x * blockDim.x + threadIdx.x;
  if (e < E) ec[e] = bt[e] * 3 + bd[e];
}

// ---------------- CSR build ----------------

__global__ void csr_count_kernel(const int* __restrict__ row, int* __restrict__ deg, int E) {
  int e = blockIdx.x * blockDim.x + threadIdx.x;
  if (e < E) atomicAdd(&deg[row[e]], 1);
}

#define SCAN_T 1024
__global__ void scan_kernel(const int* __restrict__ deg, int* __restrict__ off,
                            int* __restrict__ cur, int n) {
  __shared__ int buf[SCAN_T];
  __shared__ int carry;
  int t = threadIdx.x;
  if (t == 0) carry = 0;
  __syncthreads();
  for (int base = 0; base < n; base += SCAN_T) {
    int i = base + t;
    int v = (i < n) ? deg[i] : 0;
    buf[t] = v;
    __syncthreads();
#pragma unroll
    for (int s = 1; s < SCAN_T; s <<= 1) {
      int add = (t >= s) ? buf[t - s] : 0;
      __syncthreads();
      buf[t] += add;
      __syncthreads();
    }
    int exc = buf[t] - v + carry;
    if (i < n) {
      off[i] = exc;
      cur[i] = exc;
    }
    __syncthreads();
    if (t == SCAN_T - 1) carry += buf[SCAN_T - 1];
    __syncthreads();
  }
  if (t == 0) off[n] = carry;
}

__global__ void csr_fill_kernel(const int* __restrict__ row, const int* __restrict__ col,
                                const int* __restrict__ ec, int* __restrict__ cur,
                                int* __restrict__ scol, int* __restrict__ sec, int E) {
  int e = blockIdx.x * blockDim.x + threadIdx.x;
  if (e < E) {
    int r = row[e];
    int p = atomicAdd(&cur[r], 1);
    scol[p] = col[e];
    sec[p] = ec[e];
  }
}

// ---------------- gather (BN affine + relu folded into the h reads) ----------------

template <bool TRANS, bool RELU>
__global__ __launch_bounds__(256) void gather_kernel(
    const float* __restrict__ h, const float* __restrict__ sc, const float* __restrict__ sh,
    const int* __restrict__ off, const int* __restrict__ scol, const int* __restrict__ sec,
    const float* __restrict__ ct_l, float* __restrict__ agg, int N) {
  int wid = threadIdx.x >> 6;
  int lane = threadIdx.x & 63;
  int n = blockIdx.x * 4 + wid;
  if (n >= N) return;
  float scv[5], shv[5];
#pragma unroll
  for (int c = 0; c < 5; ++c) {
    int d = c * 64 + lane;
    if (TRANS) {
      scv[c] = (d < D_DIM) ? sc[d] : 0.f;
      shv[c] = (d < D_DIM) ? sh[d] : 0.f;
    } else {
      scv[c] = 1.f;
      shv[c] = 0.f;
    }
  }
  float acc[5];
#pragma unroll
  for (int c = 0; c < 5; ++c) {
    int d = c * 64 + lane;
    if (d < D_DIM) {
      float x = h[(size_t)n * D_DIM + d];
      float v = TRANS ? fmaf(x, scv[c], shv[c]) : x;
      if (RELU) v = fmaxf(v, 0.f);
      acc[c] = v + ct_l[12 * D_DIM + d];
    } else {
      acc[c] = 0.f;
    }
  }
  int p0 = off[n], p1 = off[n + 1];
  for (int p = p0; p < p1; ++p) {
    int scn = scol[p];
    int se = sec[p];
    const float* hp = h + (size_t)scn * D_DIM;
    const float* cp = ct_l + se * D_DIM;
#pragma unroll
    for (int c = 0; c < 5; ++c) {
      int d = c * 64 + lane;
      if (d < D_DIM) {
        float x = hp[d];
        float v = TRANS ? fmaf(x, scv[c], shv[c]) : x;
        if (RELU) v = fmaxf(v, 0.f);
        acc[c] += v + cp[d];
      }
    }
  }
#pragma unroll
  for (int c = 0; c < 5; ++c) {
    int d = c * 64 + lane;
    if (d < D_DIM) agg[(size_t)n * D_DIM + d] = acc[c];
  }
}

// ---------------- BatchNorm stats ----------------

__global__ void bn_stats_kernel(const float* __restrict__ x, float* __restrict__ stats, int N) {
  int d = threadIdx.x;
  if (d >= D_DIM) return;
  float s = 0.f, s2 = 0.f;
  for (int n = blockIdx.x; n < N; n += gridDim.x) {
    float v = x[(size_t)n * D_DIM + d];
    s += v;
    s2 += v * v;
  }
  atomicAdd(&stats[d], s);
  atomicAdd(&stats[D_DIM + d], s2);
}

__global__ void bn_final_kernel(const float* __restrict__ stats, const float* __restrict__ gamma_l,
                                const float* __restrict__ beta_l, float* __restrict__ bnsc,
                                float* __restrict__ bnsh, int N) {
  int d = threadIdx.x;
  if (d >= D_DIM) return;
  float inv_n = 1.0f / (float)N;
  float mean = stats[d] * inv_n;
  float var = stats[D_DIM + d] * inv_n - mean * mean;
  float inv = rsqrtf(var + 1e-5f);
  float sc = gamma_l[d] * inv;
  bnsc[d] = sc;
  bnsh[d] = beta_l[d] - mean * sc;
}

// ---------------- pooling (BN affine folded) ----------------

__global__ void pool_scatter_kernel(const float* __restrict__ h, const float* __restrict__ sc,
                                    const float* __restrict__ sh, const int* __restrict__ batch,
                                    float* __restrict__ pool, int* __restrict__ pcnt) {
  int n = blockIdx.x;
  int d = threadIdx.x;
  if (d >= D_DIM) return;
  int g = batch[n];
  float v = fmaf(h[(size_t)n * D_DIM + d], sc[d], sh[d]);
  atomicAdd(&pool[(size_t)g * D_DIM + d], v);
  if (d == 0) atomicAdd(&pcnt[g], 1);
}

__global__ void pool_div_kernel(float* __restrict__ pool, const int* __restrict__ pcnt) {
  int g = blockIdx.x;
  int d = threadIdx.x;
  if (d >= D_DIM) return;
  float c = (float)pcnt[g];
  if (c < 1.f) c = 1.f;
  pool[(size_t)g * D_DIM + d] /= c;
}

// ---------------- weight pack: W[K][Nw] fp32 -> MFMA-fragment-order hi/lo bf16 ----
// frag (colTile16 ct, kstep ks): lane l holds col = ct*16+(l&15), k = ks*32+(l>>4)*8..+7

__global__ void wpack_kernel(const float* __restrict__ W, bf16_t* __restrict__ Th,
                             bf16_t* __restrict__ Tl, int K, int Nw) {
  int ct = blockIdx.x;
  int ks = blockIdx.y;
  int l = threadIdx.x;
  int col = ct * 16 + (l & 15);
  int kb = ks * 32 + (l >> 4) * 8;
  unsigned short hs[8], ls[8];
#pragma unroll
  for (int j = 0; j < 8; ++j) {
    int k = kb + j;
    float v = (k < K && col < Nw) ? W[(size_t)k * Nw + col] : 0.f;
    split2(v, hs[j], ls[j]);
  }
  size_t off = ((size_t)(ct * gridDim.y + ks) * 64 + l) * 8;
  *(uint4*)(Th + off) = pack8(hs);
  *(uint4*)(Tl + off) = pack8(ls);
}

// ---------------- MFMA GEMM v3 ----------------
// C[M,Nc] = act(A[M,K] @ B[K,Nc] + bias). Block: 128 rows x 64 cols, 4 waves (2x2).
// A staged per-32-K-slab in LDS (hi/lo if fp32); row stride 80 B -> 2-way banks (free).
// B pre-packed fragment-order (coalesced, L1/L2-hot).
// Grid 1-D, XCD-grouped: all N-tiles of an M-slab land on one XCD -> A L2-reuse.

template <int KP, bool A_SPLIT, bool RELU, bool OUT_BF16>
__global__ __launch_bounds__(256, 4) void mfma_gemm3(
    const void* __restrict__ Aptr, const bf16_t* __restrict__ Bh,
    const bf16_t* __restrict__ Bl, const float* __restrict__ bias, void* __restrict__ Cptr,
    int M, int Nc, int K, int astride, int cstride, int nx, int nyT) {
  constexpr int KSTEPS = KP / 32;
  constexpr int PLANE = 128 * 80;
  __shared__ __align__(16) char lds[(A_SPLIT ? 2 : 1) * PLANE];

  // XCD-grouped decode (bijective; pad blocks exit)
  int dd = blockIdx.x;
  int xcd = dd & 7;
  int q = dd >> 3;
  int xt = q % nx;
  int yt = (q / nx) * 8 + xcd;
  if (yt >= nyT) return;
  const int m0 = yt * 128;
  const int n0 = xt * 64;

  const int t = threadIdx.x;
  const int w = t >> 6;
  const int lane = t & 63;
  const int wm = w >> 1, wn = w & 1;
  const int lrow = lane & 15;
  const int lk = lane >> 4;

  // staging mapping: thread t -> row t>>1, 16-elem k-half (t&1)
  const int sr = t >> 1;
  const int skh = (t & 1) * 16;
  const int gr = m0 + sr;
  char* sdst = lds + sr * 80 + skh * 2;

  f32x4 acc[4][2] = {};

  for (int kt = 0; kt < KSTEPS; ++kt) {
    const int kg = kt * 32 + skh;
    // ---- stage A slab ----
    if constexpr (A_SPLIT) {
      const float* arow = (const float*)Aptr + (size_t)gr * astride + kg;
      float va[16];
      if (gr < M && kg + 16 <= K) {
#pragma unroll
        for (int qd = 0; qd < 4; ++qd) {
          float4 x = ((const float4*)arow)[qd];
          va[4 * qd] = x.x;
          va[4 * qd + 1] = x.y;
          va[4 * qd + 2] = x.z;
          va[4 * qd + 3] = x.w;
        }
      } else {
#pragma unroll
        for (int j = 0; j < 16; ++j)
          va[j] = (gr < M && kg + j < K) ? arow[j] : 0.f;
      }
      unsigned short hs[16], ls[16];
#pragma unroll
      for (int j = 0; j < 16; ++j) split2(va[j], hs[j], ls[j]);
      *(uint4*)(sdst) = pack8(hs);
      *(uint4*)(sdst + 16) = pack8(hs + 8);
      *(uint4*)(sdst + PLANE) = pack8(ls);
      *(uint4*)(sdst + PLANE + 16) = pack8(ls + 8);
    } else {
      const unsigned short* arow = (const unsigned short*)Aptr + (size_t)gr * astride + kg;
      uint4 q0;
      if (gr < M && kg + 16 <= K) {
        q0 = *(const uint4*)arow;
      } else {
        unsigned short tmp[8];
#pragma unroll
        for (int j = 0; j < 8; ++j)
          tmp[j] = (gr < M && kg + j < K) ? arow[j] : (unsigned short)0;
        q0 = pack8(tmp);
      }
      uint4 q1;
      if (gr < M && kg + 16 <= K) {
        q1 = ((const uint4*)arow)[1];
      } else {
        unsigned short tmp[8];
#pragma unroll
        for (int j = 0; j < 8; ++j)
          tmp[j] = (gr < M && kg + 8 + j < K) ? arow[8 + j] : (unsigned short)0;
        q1 = pack8(tmp);
      }
      *(uint4*)(sdst) = q0;
      *(uint4*)(sdst + 16) = q1;
    }
    __syncthreads();
    // ---- fragments + MFMA ----
    bf16x8 ah[4], al[4];
#pragma unroll
    for (int i = 0; i < 4; ++i) {
      int row = wm * 64 + i * 16 + lrow;
      ah[i] = *(const bf16x8*)(const void*)(lds + row * 80 + lk * 16);
      if constexpr (A_SPLIT)
        al[i] = *(const bf16x8*)(const void*)(lds + PLANE + row * 80 + lk * 16);
    }
#pragma unroll
    for (int j = 0; j < 2; ++j) {
      int ct16 = (n0 >> 4) + wn * 2 + j;
      size_t bo = ((size_t)(ct16 * KSTEPS + kt) * 64 + lane) * 8;
      bf16x8 bh = *(const bf16x8*)(const void*)(Bh + bo);
      bf16x8 bl = *(const bf16x8*)(const void*)(Bl + bo);
#pragma unroll
      for (int i = 0; i < 4; ++i) {
        acc[i][j] = mfma16(ah[i], bh, acc[i][j]);
        acc[i][j] = mfma16(ah[i], bl, acc[i][j]);
        if constexpr (A_SPLIT) acc[i][j] = mfma16(al[i], bh, acc[i][j]);
      }
    }
    __syncthreads();
  }

  // ---- epilogue ----
#pragma unroll
  for (int j = 0; j < 2; ++j) {
    int gcol = n0 + wn * 32 + j * 16 + lrow;
    if (gcol >= Nc) continue;
    float bsv = bias[gcol];
#pragma unroll
    for (int i = 0; i < 4; ++i) {
#pragma unroll
      for (int r4 = 0; r4 < 4; ++r4) {
        int grow = m0 + wm * 64 + i * 16 + lk * 4 + r4;
        if (grow < M) {
          float v = acc[i][j][r4] + bsv;
          if (RELU) v = fmaxf(v, 0.f);
          if constexpr (OUT_BF16)
            ((bf16_t*)Cptr)[(size_t)grow * cstride + gcol] = (bf16_t)v;
          else
            ((float*)Cptr)[(size_t)grow * cstride + gcol] = v;
        }
      }
    }
  }
}

// ---------------- launch ----------------

extern "C" void kernel_launch(void* const* d_in, const int* in_sizes, int n_in,
                              void* d_out, int out_size, void* d_ws, size_t ws_size,
                              hipStream_t stream) {
  const int* atom = (const int*)d_in[0];
  const int* chir = (const int*)d_in[1];
  const int* eidx = (const int*)d_in[2];
  const int* btype = (const int*)d_in[3];
  const int* bdir = (const int*)d_in[4];
  const int* batch = (const int*)d_in[5];
  const float* x_emb1 = (const float*)d_in[6];
  const float* x_emb2 = (const float*)d_in[7];
  const float* ee1 = (const float*)d_in[8];
  const float* ee2 = (const float*)d_in[9];
  const float* W1 = (const float*)d_in[10];
  const float* b1 = (const float*)d_in[11];
  const float* W2 = (const float*)d_in[12];
  const float* b2 = (const float*)d_in[13];
  const float* gamma = (const float*)d_in[14];
  const float* beta = (const float*)d_in[15];
  const float* featW = (const float*)d_in[16];
  const float* featb = (const float*)d_in[17];
  const float* projW = (const float*)d_in[18];
  const float* projb = (const float*)d_in[19];

  const int N = in_sizes[0];
  const int E = in_sizes[2] / 2;
  const int PROJ = in_sizes[19];
  const int FEAT = in_sizes[17];
  const int G = out_size / PROJ;
  const int L = in_sizes[11] / (2 * D_DIM);
  const int D2 = 2 * D_DIM;  // 600

  const int* row = eidx;
  const int* col = eidx + E;

  // B-table geometry: CT16 = 16-col tiles, KS = K-steps of 32
  const int CT16_1 = 40, KS_1 = 10;  // W1: K=300->KP320, N=600->640
  const int CT16_2 = 20, KS_2 = 19;  // W2: K=600->KP608, N=300->320
  const int CT16_F = 32, KS_F = 10;  // feat: K=300->320, N=512
  const int CT16_P = 16, KS_P = 16;  // proj: K=512, N=256
  const int SZ1 = CT16_1 * KS_1 * 512;
  const int SZ2 = CT16_2 * KS_2 * 512;
  const int SZF = CT16_F * KS_F * 512;
  const int SZP = CT16_P * KS_P * 512;

  // ---- workspace ----
  char* ws = (char*)d_ws;
  size_t off = 0;
  auto alloc = [&](size_t bytes) -> char* {
    char* p = ws + off;
    off += (bytes + 255) & ~(size_t)255;
    return p;
  };
  float* B0 = (float*)alloc((size_t)N * D_DIM * 4);
  float* B1 = (float*)alloc((size_t)N * D_DIM * 4);
  float* CT = (float*)alloc((size_t)L * 13 * D_DIM * 4);
  int* EC = (int*)alloc((size_t)E * 4);
  int* DEG = (int*)alloc((size_t)N * 4);
  int* OFF = (int*)alloc((size_t)(N + 1) * 4);
  int* CUR = (int*)alloc((size_t)N * 4);
  int* SCOL = (int*)alloc((size_t)E * 4);
  int* SEC = (int*)alloc((size_t)E * 4);
  float* STATS = (float*)alloc(2 * D_DIM * 4);
  float* BNSC = (float*)alloc(D_DIM * 4);
  float* BNSH = (float*)alloc(D_DIM * 4);
  bf16_t* W1Th = (bf16_t*)alloc((size_t)L * SZ1 * 2);
  bf16_t* W1Tl = (bf16_t*)alloc((size_t)L * SZ1 * 2);
  bf16_t* W2Th = (bf16_t*)alloc((size_t)L * SZ2 * 2);
  bf16_t* W2Tl = (bf16_t*)alloc((size_t)L * SZ2 * 2);
  bf16_t* FTh = (bf16_t*)alloc((size_t)SZF * 2);
  bf16_t* FTl = (bf16_t*)alloc((size_t)SZF * 2);
  bf16_t* PTh = (bf16_t*)alloc((size_t)SZP * 2);
  bf16_t* PTl = (bf16_t*)alloc((size_t)SZP * 2);
  (void)ws_size;

  // ---- prep ----
  init_h_kernel<<<N, TPB, 0, stream>>>(atom, chir, x_emb1, x_emb2, B0);
  combo_kernel<<<L * 13, TPB, 0, stream>>>(ee1, ee2, CT);
  edge_combo_kernel<<<(E + 255) / 256, 256, 0, stream>>>(btype, bdir, EC, E);

  zero_u32_kernel<<<(N + 255) / 256, 256, 0, stream>>>((unsigned int*)DEG, N);
  csr_count_kernel<<<(E + 255) / 256, 256, 0, stream>>>(row, DEG, E);
  scan_kernel<<<1, SCAN_T, 0, stream>>>(DEG, OFF, CUR, N);
  csr_fill_kernel<<<(E + 255) / 256, 256, 0, stream>>>(row, col, EC, CUR, SCOL, SEC, E);

  for (int l = 0; l < L; ++l) {
    wpack_kernel<<<dim3(CT16_1, KS_1), 64, 0, stream>>>(
        W1 + (size_t)l * D_DIM * D2, W1Th + (size_t)l * SZ1, W1Tl + (size_t)l * SZ1, D_DIM, D2);
    wpack_kernel<<<dim3(CT16_2, KS_2), 64, 0, stream>>>(
        W2 + (size_t)l * D2 * D_DIM, W2Th + (size_t)l * SZ2, W2Tl + (size_t)l * SZ2, D2, D_DIM);
  }
  wpack_kernel<<<dim3(CT16_F, KS_F), 64, 0, stream>>>(featW, FTh, FTl, D_DIM, FEAT);
  wpack_kernel<<<dim3(CT16_P, KS_P), 64, 0, stream>>>(projW, PTh, PTl, FEAT, PROJ);

  float* hbuf = B0;  // raw h2 of previous layer (layer 0: initial h)
  float* sbuf = B1;
  const int nyT = (N + 127) / 128;            // M-tiles
  const int ny8 = ((nyT + 7) / 8) * 8;        // padded for XCD decode
  const int g1 = 10 * ny8;                    // GEMM1 grid
  const int g2 = 5 * ny8;                     // GEMM2 grid
  const int nyG = (G + 127) / 128;
  const int nyG8 = ((nyG + 7) / 8) * 8;

  for (int l = 0; l < L; ++l) {
    const float* ctl = CT + (size_t)l * 13 * D_DIM;
    if (l == 0)
      gather_kernel<false, false><<<(N + 3) / 4, 256, 0, stream>>>(hbuf, BNSC, BNSH, OFF, SCOL,
                                                                   SEC, ctl, sbuf, N);
    else
      gather_kernel<true, true><<<(N + 3) / 4, 256, 0, stream>>>(hbuf, BNSC, BNSH, OFF, SCOL,
                                                                 SEC, ctl, sbuf, N);
    // hid = relu(agg @ W1 + b1) -> bf16 [N][600] into hbuf (prev h dead)
    mfma_gemm3<320, true, true, true><<<g1, 256, 0, stream>>>(
        sbuf, W1Th + (size_t)l * SZ1, W1Tl + (size_t)l * SZ1, b1 + (size_t)l * D2, hbuf, N, D2,
        D_DIM, D_DIM, D2, 10, nyT);
    // h2 = hid @ W2 + b2 -> fp32 [N][300] into sbuf (agg dead)
    mfma_gemm3<608, false, false, false><<<g2, 256, 0, stream>>>(
        hbuf, W2Th + (size_t)l * SZ2, W2Tl + (size_t)l * SZ2, b2 + (size_t)l * D_DIM, sbuf, N,
        D_DIM, D2, D2, D_DIM, 5, nyT);
    // BN stats of raw h2 (affine folded into next consumer)
    zero_u32_kernel<<<2, 320, 0, stream>>>((unsigned int*)STATS, 2 * D_DIM);
    bn_stats_kernel<<<512, TPB, 0, stream>>>(sbuf, STATS, N);
    bn_final_kernel<<<1, TPB, 0, stream>>>(STATS, gamma + (size_t)l * D_DIM,
                                           beta + (size_t)l * D_DIM, BNSC, BNSH, N);
    float* tmp = hbuf;
    hbuf = sbuf;
    sbuf = tmp;
  }

  // final raw h2 in hbuf (last BN folded into pool); sbuf free
  float* POOL = sbuf;
  int* PCNT = (int*)(POOL + (size_t)G * D_DIM);
  float* FEATB = (float*)(PCNT + G);

  {
    long long nz = (long long)G * D_DIM + G;
    int blocks = (int)((nz + 255) / 256);
    if (blocks > 2048) blocks = 2048;
    zero_u32_kernel<<<blocks, 256, 0, stream>>>((unsigned int*)POOL, nz);
  }
  pool_scatter_kernel<<<N, TPB, 0, stream>>>(hbuf, BNSC, BNSH, batch, POOL, PCNT);
  pool_div_kernel<<<G, TPB, 0, stream>>>(POOL, PCNT);

  mfma_gemm3<320, true, false, false><<<8 * nyG8, 256, 0, stream>>>(
      POOL, FTh, FTl, featb, FEATB, G, FEAT, D_DIM, D_DIM, FEAT, 8, nyG);
  mfma_gemm3<512, true, false, false><<<4 * nyG8, 256, 0, stream>>>(
      FEATB, PTh, PTl, projb, d_out, G, PROJ, FEAT, FEAT, PROJ, 4, nyG);
}